// Round 9
// baseline (357.985 us; speedup 1.0000x reference)
//
#include <hip/hip_runtime.h>
#include <cstdint>
#include <cstddef>

#define S_LEN 384
#define BATCH 256
#define DIM   192     // HH*WW
#define HID   100
#define G4    400     // 4*HID
#define NCLS  250

#define LOG2E  1.4426950408889634f
#define LOG2E2 2.8853900817779268f

typedef float    f32x4   __attribute__((ext_vector_type(4)));
typedef short    bf16x8  __attribute__((ext_vector_type(8)));
typedef _Float16 half2_t __attribute__((ext_vector_type(2)));
typedef _Float16 f16x4   __attribute__((ext_vector_type(4)));
typedef _Float16 f16x8   __attribute__((ext_vector_type(8)));

static __device__ __forceinline__ unsigned short f2bf(float f) {
    unsigned u = __float_as_uint(f);
    return (unsigned short)((u + 0x7FFFu + ((u >> 16) & 1u)) >> 16);   // RNE
}

// DPP quad_perm cross-lane (VALU ~2cyc)
template<int CTRL>
static __device__ __forceinline__ float fdpp(float x) {
    return __int_as_float(
        __builtin_amdgcn_mov_dpp(__float_as_int(x), CTRL, 0xF, 0xF, true));
}
#define DPP_X1 0xB1   // quad_perm [1,0,3,2]  == xor 1
#define DPP_X2 0x4E   // quad_perm [2,3,0,1]  == xor 2
#define DPP_B0 0x00   // quad_perm [0,0,0,0]  broadcast lane0 of quad
#define DPP_B1 0x55   // quad_perm [1,1,1,1]
#define DPP_B2 0xAA   // quad_perm [2,2,2,2]
#define DPP_B3 0xFF   // quad_perm [3,3,3,3]

// ---------------------------------------------------------------------------
// Kernel 1 (round 9): verified MFMA GEMM compute + r8 coalesced epilogue,
//   now SELF-STAGING from raw W (prep kernel deleted — each launch costs
//   ~30us of graph-replay gap; prep existed only for layout transforms).
//   Per dc: read 32 coalesced rows of W (d = dc*32 + 2*rp (+1), 1600B each)
//   and write the IDENTICAL wsh uint layout as the old Wt path:
//   wsh[k*20 + dd/2] = bf16(W[dc*32+dd][k]) | bf16(W[dc*32+dd+1][k])<<16.
//   Writes are 4B, stride 80 dwords -> 2-way bank aliasing (free, m136).
// ---------------------------------------------------------------------------
__global__ __launch_bounds__(256, 2)
void gemm_pre(const float* __restrict__ x, const float* __restrict__ Wg,
              const float* __restrict__ bias, _Float16* __restrict__ preh,
              int s_start, int chunk)
{
    __shared__ __align__(16) unsigned char smem[57600];
    unsigned int* xs  = (unsigned int*)smem;             // 64*100 uint (25.6KB)
    unsigned int* wsh = (unsigned int*)(smem + 25600);   // 400*20 uint (32KB)
    _Float16*     Cl  = (_Float16*)smem;                 // 400*72 f16 (57.6KB) after reuse

    const int t    = threadIdx.x;
    const int lane = t & 63;
    const int w    = t >> 6;
    const int nsb  = chunk >> 6;
    const int b    = blockIdx.x / nsb;
    const int sblk = blockIdx.x - b * nsb;
    const float* __restrict__ xb = x + ((size_t)b * S_LEN + s_start + sblk * 64) * DIM;

#pragma unroll
    for (int r = 0; r < 12; ++r) {
        int i = t + r * 256;                 // 3072 float4 = 64 rows x 48
        int row = i / 48, c4 = i - row * 48;
        float4 v = ((const float4*)(xb + (size_t)row * DIM))[c4];
        xs[row * 100 + c4 * 2]     = (unsigned)f2bf(v.x) | ((unsigned)f2bf(v.y) << 16);
        xs[row * 100 + c4 * 2 + 1] = (unsigned)f2bf(v.z) | ((unsigned)f2bf(v.w) << 16);
    }

    const int m = lane & 15, q = lane >> 4;

    float bv[25];
#pragma unroll
    for (int ct = 0; ct < 25; ++ct) bv[ct] = bias[ct * 16 + m];

    f32x4 acc[25];
#pragma unroll
    for (int ct = 0; ct < 25; ++ct) acc[ct] = (f32x4){0.f, 0.f, 0.f, 0.f};

    for (int dc = 0; dc < 6; ++dc) {
        if (dc) __syncthreads();             // protect previous chunk's readers
#pragma unroll
        for (int r = 0; r < 7; ++r) {
            int i = t + r * 256;
            if (i < 1600) {                  // 16 d-pairs x 100 k-quads
                int rp = i / 100, c4 = i - rp * 100;
                const float* wp = Wg + ((size_t)(dc * 32 + 2 * rp) * G4 + c4 * 4);
                float4 w0 = *(const float4*)wp;          // row d   (coalesced)
                float4 w1 = *(const float4*)(wp + G4);   // row d+1 (coalesced)
                wsh[(c4 * 4 + 0) * 20 + rp] = (unsigned)f2bf(w0.x) | ((unsigned)f2bf(w1.x) << 16);
                wsh[(c4 * 4 + 1) * 20 + rp] = (unsigned)f2bf(w0.y) | ((unsigned)f2bf(w1.y) << 16);
                wsh[(c4 * 4 + 2) * 20 + rp] = (unsigned)f2bf(w0.z) | ((unsigned)f2bf(w1.z) << 16);
                wsh[(c4 * 4 + 3) * 20 + rp] = (unsigned)f2bf(w0.w) | ((unsigned)f2bf(w1.w) << 16);
            }
        }
        __syncthreads();

        const unsigned short* xp = (const unsigned short*)xs
                                   + (16 * w + m) * 200 + dc * 32 + q * 8;
        bf16x8 af = *(const bf16x8*)xp;
#pragma unroll
        for (int ct = 0; ct < 25; ++ct) {
            const unsigned short* bp = (const unsigned short*)wsh
                                       + (ct * 16 + m) * 40 + q * 8;
            bf16x8 bf = *(const bf16x8*)bp;
            acc[ct] = __builtin_amdgcn_mfma_f32_16x16x32_bf16(af, bf, acc[ct], 0, 0, 0);
        }
    }

    // ---- r8 epilogue: LDS transpose staging + coalesced stores ----
    __syncthreads();                         // all waves done reading xs/wsh
#pragma unroll
    for (int ct = 0; ct < 25; ++ct) {
        f16x4 v;
        v[0] = (_Float16)(acc[ct][0] + bv[ct]);
        v[1] = (_Float16)(acc[ct][1] + bv[ct]);
        v[2] = (_Float16)(acc[ct][2] + bv[ct]);
        v[3] = (_Float16)(acc[ct][3] + bv[ct]);
        *(f16x4*)&Cl[(ct * 16 + m) * 72 + 16 * w + q * 4] = v;   // 8B, 8B-aligned
    }
    __syncthreads();

    _Float16* __restrict__ pb = preh + (size_t)b * G4 * chunk + (size_t)sblk * 64;
    const int lane8 = t & 7, rbase = t >> 3;
#pragma unroll
    for (int p = 0; p < 13; ++p) {
        int r = p * 32 + rbase;              // k row
        if (r < G4) {
            f16x8 vv = *(const f16x8*)&Cl[r * 72 + lane8 * 8];   // 16B, 16B-aligned
            *(f16x8*)(pb + (size_t)r * chunk + lane8 * 8) = vv;  // coalesced 128B/row
        }
    }
}

// ---------------------------------------------------------------------------
// Kernel 2: the VERIFIED r1 scan core (176.3us), with U fragments gathered
//   directly from the raw U matrix at init (identical index math to the old
//   prep; 104 L2-hot loads per thread, one-time) — removes the prep launch.
// ---------------------------------------------------------------------------
__global__ __launch_bounds__(512, 2)
void lstm_scan(const _Float16* __restrict__ preh, const float* __restrict__ U,
               const float* __restrict__ Wd, const float* __restrict__ bd,
               float* __restrict__ out, float* __restrict__ state,
               int nsteps, int first, int last)
{
    __shared__ __align__(16) _Float16 h2[2][4][40];
    __shared__ __align__(16) float hf32[HID];

    const int b  = blockIdx.x;
    const int t  = threadIdx.x;
    const int q  = t & 3;
    const int nr = t >> 2;                   // 0..127
    const bool active = (nr < HID);
    const int n  = active ? nr : HID - 1;
    const int wq = n / 26, wi = n - wq * 26;

    // Uc[m][r]: gate (q^m), h-elems 26q+2r, 26q+2r+1 (old prep mapping)
    half2_t Uc[4][13];
#pragma unroll
    for (int mm = 0; mm < 4; ++mm) {
        const int col = (q ^ mm) * HID + n;
#pragma unroll
        for (int r = 0; r < 13; ++r) {
            const int j0 = 26 * q + 2 * r;
            half2_t v;
            v.x = (_Float16)(j0     < HID ? U[(size_t)j0       * G4 + col] : 0.0f);
            v.y = (_Float16)(j0 + 1 < HID ? U[(size_t)(j0 + 1) * G4 + col] : 0.0f);
            Uc[mm][r] = v;
        }
    }

    if (t < 320) ((_Float16*)h2)[t] = (_Float16)0.f;
    float c;
    if (first) {
        c = 0.f;
        __syncthreads();
    } else {
        c = state[BATCH * HID + b * HID + n];
        __syncthreads();
        if (t < HID) h2[0][t / 26][t - (t / 26) * 26] = (_Float16)state[b * HID + t];
        __syncthreads();
    }

    const _Float16* __restrict__ zp = preh + ((size_t)b * G4 + q * HID + n) * nsteps;

    const float scale = (q == 2) ? -LOG2E2 : -LOG2E;
    const float Aact  = (q == 2) ? 2.0f : 1.0f;
    const float Bact  = (q == 2) ? -1.0f : 0.0f;

    float hn_last = 0.f;

    auto step = [&](float zk, int cur) {
        const _Float16* hb = &h2[cur][q][0];
        f16x8   g0 = *(const f16x8*)(hb);
        f16x8   g1 = *(const f16x8*)(hb + 8);
        f16x8   g2 = *(const f16x8*)(hb + 16);
        half2_t g3 = *(const half2_t*)(hb + 24);
        half2_t hp[13];
        hp[0]  = __builtin_shufflevector(g0, g0, 0, 1);
        hp[1]  = __builtin_shufflevector(g0, g0, 2, 3);
        hp[2]  = __builtin_shufflevector(g0, g0, 4, 5);
        hp[3]  = __builtin_shufflevector(g0, g0, 6, 7);
        hp[4]  = __builtin_shufflevector(g1, g1, 0, 1);
        hp[5]  = __builtin_shufflevector(g1, g1, 2, 3);
        hp[6]  = __builtin_shufflevector(g1, g1, 4, 5);
        hp[7]  = __builtin_shufflevector(g1, g1, 6, 7);
        hp[8]  = __builtin_shufflevector(g2, g2, 0, 1);
        hp[9]  = __builtin_shufflevector(g2, g2, 2, 3);
        hp[10] = __builtin_shufflevector(g2, g2, 4, 5);
        hp[11] = __builtin_shufflevector(g2, g2, 6, 7);
        hp[12] = g3;

        float p0 = 0.f, p1 = 0.f, p2 = 0.f, p3 = 0.f;
#pragma unroll
        for (int r = 0; r < 13; ++r) {
            p0 = __builtin_amdgcn_fdot2(Uc[0][r], hp[r], p0, false);
            p1 = __builtin_amdgcn_fdot2(Uc[1][r], hp[r], p1, false);
            p2 = __builtin_amdgcn_fdot2(Uc[2][r], hp[r], p2, false);
            p3 = __builtin_amdgcn_fdot2(Uc[3][r], hp[r], p3, false);
        }
        float s0 = p0 + fdpp<DPP_X1>(p1);
        float s2 = p2 + fdpp<DPP_X1>(p3);
        float a  = s0 + fdpp<DPP_X2>(s2) + zk;

        float v = fmaf(Aact,
                       __builtin_amdgcn_rcpf(1.0f + __builtin_amdgcn_exp2f(scale * a)),
                       Bact);

        float bi = fdpp<DPP_B0>(v);
        float bf = fdpp<DPP_B1>(v);
        float bg = fdpp<DPP_B2>(v);
        float bo = fdpp<DPP_B3>(v);

        c = fmaf(bf, c, bi * bg);
        float tc = fmaf(2.0f,
                        __builtin_amdgcn_rcpf(1.0f + __builtin_amdgcn_exp2f(-LOG2E2 * c)),
                        -1.0f);
        float hn = bo * tc;
        if (q == 0 && active) h2[cur ^ 1][wq][wi] = (_Float16)hn;
        hn_last = hn;
        __syncthreads();
    };

    f16x8 zv = *(const f16x8*)(zp);
    for (int s8 = 0; s8 < nsteps; s8 += 8) {            // nsteps % 8 == 0
        f16x8 zvn = zv;
        if (s8 + 8 < nsteps) zvn = *(const f16x8*)(zp + s8 + 8);   // prefetch
#pragma unroll
        for (int k = 0; k < 8; ++k)
            step((float)zv[k], k & 1);
        zv = zvn;
    }

    if (last) {
        if (q == 0 && active) hf32[n] = hn_last;
        __syncthreads();
        if (t < NCLS) {
            float acc2 = bd[t];
            const float4* h4 = (const float4*)hf32;
#pragma unroll 5
            for (int j4 = 0; j4 < 25; ++j4) {
                float4 hv = h4[j4];
                acc2 = fmaf(hv.x, Wd[(size_t)(4 * j4 + 0) * NCLS + t], acc2);
                acc2 = fmaf(hv.y, Wd[(size_t)(4 * j4 + 1) * NCLS + t], acc2);
                acc2 = fmaf(hv.z, Wd[(size_t)(4 * j4 + 2) * NCLS + t], acc2);
                acc2 = fmaf(hv.w, Wd[(size_t)(4 * j4 + 3) * NCLS + t], acc2);
            }
            out[(size_t)b * NCLS + t] = acc2;
        }
    } else {
        if (q == 0 && active) {
            state[b * HID + n] = hn_last;
            state[BATCH * HID + b * HID + n] = c;
        }
    }
}

// ---------------------------------------------------------------------------
extern "C" void kernel_launch(void* const* d_in, const int* in_sizes, int n_in,
                              void* d_out, int out_size, void* d_ws, size_t ws_size,
                              hipStream_t stream)
{
    const float* x    = (const float*)d_in[0];
    const float* W    = (const float*)d_in[1];
    const float* U    = (const float*)d_in[2];
    const float* bias = (const float*)d_in[3];
    const float* Wd   = (const float*)d_in[4];
    const float* bd   = (const float*)d_in[5];
    float* out = (float*)d_out;

    // ws (dwords): [state 51200][preh f16: chunk*51200 dw]
    const size_t fixed_dw = 51200;
    int chunk = 64;
    if      (ws_size >= (fixed_dw + (size_t)384 * 51200) * 4) chunk = 384;
    else if (ws_size >= (fixed_dw + (size_t)192 * 51200) * 4) chunk = 192;
    const int nchunks = S_LEN / chunk;

    unsigned int* wsb = (unsigned int*)d_ws;
    float*    state = (float*)wsb;
    _Float16* preh  = (_Float16*)(wsb + 51200);

    for (int ci = 0; ci < nchunks; ++ci) {
        const int s0 = ci * chunk;
        gemm_pre<<<BATCH * (chunk >> 6), 256, 0, stream>>>(x, W, bias, preh, s0, chunk);
        lstm_scan<<<BATCH, 512, 0, stream>>>(preh, U, Wd, bd, out, state,
                                             chunk, ci == 0 ? 1 : 0,
                                             ci == nchunks - 1 ? 1 : 0);
    }
}

// Round 11
// 356.805 us; speedup vs baseline: 1.0033x; 1.0033x over previous
//
#include <hip/hip_runtime.h>
#include <cstdint>
#include <cstddef>

#define S_LEN 384
#define BATCH 256
#define DIM   192     // HH*WW
#define HID   100
#define G4    400     // 4*HID
#define NCLS  250

#define WSTEPS 16     // z-tile window (MFMA M-dim = 16 timesteps)
#define NWIN   24     // 384 / 16
#define NTILES 28     // 448 cols (4 gates x 112) / 16
#define NKC    6      // 192 / 32 k-chunks

#define LOG2E  1.4426950408889634f
#define LOG2E2 2.8853900817779268f

typedef float    f32x4   __attribute__((ext_vector_type(4)));
typedef short    bf16x8  __attribute__((ext_vector_type(8)));
typedef _Float16 half2_t __attribute__((ext_vector_type(2)));
typedef _Float16 f16x4   __attribute__((ext_vector_type(4)));
typedef _Float16 f16x8   __attribute__((ext_vector_type(8)));

static __device__ __forceinline__ unsigned short f2bf(float f) {
    unsigned u = __float_as_uint(f);
    return (unsigned short)((u + 0x7FFFu + ((u >> 16) & 1u)) >> 16);   // RNE
}

// packed f32x2 -> bf16x2 (RNE)
static __device__ __forceinline__ unsigned cvtpk(float a, float b) {
    unsigned r;
    asm("v_cvt_pk_bf16_f32 %0, %1, %2" : "=v"(r) : "v"(a), "v"(b));
    return r;
}

// DPP quad_perm cross-lane (VALU ~2cyc)
template<int CTRL>
static __device__ __forceinline__ float fdpp(float x) {
    return __int_as_float(
        __builtin_amdgcn_mov_dpp(__float_as_int(x), CTRL, 0xF, 0xF, true));
}
#define DPP_X1 0xB1   // quad_perm [1,0,3,2]  == xor 1
#define DPP_X2 0x4E   // quad_perm [2,3,0,1]  == xor 2
#define DPP_B0 0x00   // quad_perm [0,0,0,0]  broadcast lane0 of quad
#define DPP_B1 0x55   // quad_perm [1,1,1,1]
#define DPP_B2 0xAA   // quad_perm [2,2,2,2]
#define DPP_B3 0xFF   // quad_perm [3,3,3,3]

// ---------------------------------------------------------------------------
// Prep (verified r7): Wf MFMA B-fragments + biasf + Ut4.
// ---------------------------------------------------------------------------
__global__ void prep(const float* __restrict__ W, const float* __restrict__ U,
                     const float* __restrict__ bias,
                     unsigned short* __restrict__ Wf, float* __restrict__ biasf,
                     half2_t* __restrict__ Ut4)
{
    int bid = blockIdx.x;
    if (bid < 336) {
        int i = bid * 256 + threadIdx.x;          // 336*256 = 86016 exactly
        int e    = i & 7;
        int fi   = i >> 3;
        int lane = fi & 63;
        int ck   = fi >> 6;                       // (ct*6+kc) < 168
        int ct   = ck / 6, kc = ck - ct * 6;
        int m    = lane & 15, q = lane >> 4;
        int gate = ct / 7, jj = ct - gate * 7;
        int unit = jj * 16 + m;
        int d    = kc * 32 + q * 8 + e;           // < 192 always
        float v  = (unit < HID) ? W[(size_t)d * G4 + gate * HID + unit] : 0.0f;
        Wf[i] = f2bf(v);
    } else {
        int i = (bid - 336) * 256 + threadIdx.x;  // 448 + 20800 = 21248
        if (i < 448) {
            int ct = i >> 4, mm = i & 15;
            int gate = ct / 7, jj = ct - gate * 7;
            int unit = jj * 16 + mm;
            biasf[i] = (unit < HID) ? bias[gate * HID + unit] : 0.0f;
        } else {
            int i2 = i - 448;
            if (i2 >= 20800) return;
            int n    = i2 / 208;
            int rem  = i2 - n * 208;
            int q    = rem / 52;
            int rem2 = rem - q * 52;
            int mm   = rem2 / 13;
            int r    = rem2 - mm * 13;
            int col  = (q ^ mm) * HID + n;
            int j0   = 26 * q + 2 * r;
            half2_t v;
            v.x = (_Float16)(j0     < HID ? U[(size_t)j0       * G4 + col] : 0.0f);
            v.y = (_Float16)(j0 + 1 < HID ? U[(size_t)(j0 + 1) * G4 + col] : 0.0f);
            Ut4[i2] = v;
        }
    }
}

// ---------------------------------------------------------------------------
// Fused kernel, round 11 (= r10 compile-fixed): r7 structure (waves 0-6
// scan, 7-8 producers), producer re-scheduled to break load->MFMA
// serialization via register double-buffering.
//   r10 compile fix: HIP float4 is a class type -> illegal in "+v" asm
//   constraints ("tied indirect register inputs"); use plain ext-vector
//   f32x4 for the pinned xv registers instead.
//   r6/r7 pathology (measured 1540-1730cy/step): compiler orders each tile
//   as load->waitcnt->MFMA x6 => ~1500cy/slot of exposed L2 latency INSIDE
//   the barrier interval. Fix: slot k prefetches tile k+1's Bf into the
//   alternate bank (asm-pinned so loads issue NOW, drain at the slot
//   barrier under the scan's ~1100cy step), MFMAs read the current bank.
//   Bias hoisted to 14 resident floats; xv pinned after LOADX so the x
//   prefetch really issues 2 windows ahead (r7 VGPR=72 proved sinking).
// Barrier counts unchanged from r7 (verified): 1 + 24*16 + 1 per wave.
// ---------------------------------------------------------------------------
__global__ __launch_bounds__(576)
__attribute__((amdgpu_waves_per_eu(2)))
void scan_fused(const float* __restrict__ x, const unsigned short* __restrict__ Wf,
                const half2_t* __restrict__ Ut4, const float* __restrict__ biasf,
                const float* __restrict__ Wd, const float* __restrict__ bd,
                float* __restrict__ out)
{
    __shared__ __align__(16) _Float16 h2[2][4][40];
    __shared__ __align__(16) float hf32[HID];
    __shared__ __align__(16) _Float16 zbuf[2][448 * WSTEPS];   // 28.7 KB

    const int b    = blockIdx.x;
    const int t    = threadIdx.x;
    const int lane = t & 63;
    const int w    = t >> 6;

    if (t < 320) ((_Float16*)h2)[t] = (_Float16)0.f;   // zero both h bufs

    if (w >= 7) {
        // ===================== PRODUCER WAVES (2) =====================
        const int po = w - 7;            // 0: tiles [0,14), 1: tiles [14,28)
        const int tb = po * 14;
        const int pm = lane & 15;        // step row within window
        const int pq = lane >> 4;        // k-slice
        const float* __restrict__ xb = x + (size_t)b * S_LEN * DIM;
        f32x4  xv[NKC][2];               // next window's x rows (pinned)
        bf16x8 Af[NKC];                  // current produce window's A frags
        bf16x8 Ba[NKC], Bb[NKC];         // double-buffered W fragments

        float bvs[14];                   // bias: same every window, resident
#pragma unroll
        for (int i = 0; i < 14; ++i) bvs[i] = biasf[(tb + i) * 16 + pm];

#define LOADX(S0)                                                             \
    { int xr = (S0) + pm;                                                     \
      _Pragma("unroll")                                                       \
      for (int kc = 0; kc < NKC; ++kc) {                                      \
          const float* p_ = xb + (size_t)xr * DIM + kc * 32 + pq * 8;         \
          xv[kc][0] = *(const f32x4*)p_;                                      \
          xv[kc][1] = *(const f32x4*)(p_ + 4);                                \
      }                                                                       \
      asm volatile("" : "+v"(xv[0][0]), "+v"(xv[0][1]), "+v"(xv[1][0]),       \
                        "+v"(xv[1][1]), "+v"(xv[2][0]), "+v"(xv[2][1]),       \
                        "+v"(xv[3][0]), "+v"(xv[3][1]), "+v"(xv[4][0]),       \
                        "+v"(xv[4][1]), "+v"(xv[5][0]), "+v"(xv[5][1])); }

#define CVTA()                                                                \
    { _Pragma("unroll")                                                       \
      for (int kc = 0; kc < NKC; ++kc) {                                      \
          int4 ai_;                                                           \
          ai_.x = (int)cvtpk(xv[kc][0][0], xv[kc][0][1]);                     \
          ai_.y = (int)cvtpk(xv[kc][0][2], xv[kc][0][3]);                     \
          ai_.z = (int)cvtpk(xv[kc][1][0], xv[kc][1][1]);                     \
          ai_.w = (int)cvtpk(xv[kc][1][2], xv[kc][1][3]);                     \
          Af[kc] = *(bf16x8*)&ai_;                                            \
      } }

#define LOADB(CT, DST)                                                        \
    { const unsigned short* bp_ = Wf + ((size_t)(CT) * (NKC * 64) + lane) * 8;\
      _Pragma("unroll")                                                       \
      for (int kc = 0; kc < NKC; ++kc)                                        \
          DST[kc] = *(const bf16x8*)(bp_ + (size_t)kc * 512);                 \
      asm volatile("" : "+v"(DST[0]), "+v"(DST[1]), "+v"(DST[2]),             \
                        "+v"(DST[3]), "+v"(DST[4]), "+v"(DST[5])); }

#define CTILE(CT, SRC, BV, NB)                                                \
    { f32x4 acc_ = {0.f, 0.f, 0.f, 0.f};                                      \
      _Pragma("unroll")                                                       \
      for (int kc = 0; kc < NKC; ++kc)                                        \
          acc_ = __builtin_amdgcn_mfma_f32_16x16x32_bf16(Af[kc], SRC[kc],     \
                                                         acc_, 0, 0, 0);      \
      f16x4 zq_;                                                              \
      zq_[0] = (_Float16)(acc_[0] + (BV));                                    \
      zq_[1] = (_Float16)(acc_[1] + (BV));                                    \
      zq_[2] = (_Float16)(acc_[2] + (BV));                                    \
      zq_[3] = (_Float16)(acc_[3] + (BV));                                    \
      *(f16x4*)&zbuf[NB][((CT) * 16 + pm) * WSTEPS + pq * 4] = zq_; }

        // prologue: window 0 into zbuf[0] (one-time, serial is fine);
        // prefetch x(window 1); preload slot-0 tile into Ba.
        LOADX(0);
        CVTA();
#pragma unroll
        for (int i = 0; i < 14; ++i) {
            LOADB(tb + i, Bb)
            CTILE(tb + i, Bb, bvs[i], 0)
        }
        LOADX(WSTEPS);
        LOADB(tb, Ba)
        __syncthreads();                              // barrier #0

        for (int j = 0; j < NWIN; ++j) {
            const bool hasNext = (j < NWIN - 1);
            if (hasNext) CVTA();                      // Af for window j+1
            if (j < NWIN - 2) LOADX((j + 2) * WSTEPS);
            const int nb = (j + 1) & 1;
#pragma unroll
            for (int k = 0; k < WSTEPS; ++k) {
                if (hasNext && k <= 13) {
                    // prefetch next slot's tile into the alternate bank
                    const int nt = (k <= 12) ? (tb + k + 1) : tb;  // k=13: next window slot 0
                    if (k & 1) { LOADB(nt, Ba) } else { LOADB(nt, Bb) }
                    // compute this slot's tile from the current bank
                    if (k & 1) { CTILE(tb + k, Bb, bvs[k], nb) }
                    else       { CTILE(tb + k, Ba, bvs[k], nb) }
                }
                __syncthreads();
            }
        }
        __syncthreads();                              // matches scan tail barrier
    } else {
        // ===================== SCAN WAVES (verified r1 core) =====================
        const int q  = t & 3;
        const int nr = t >> 2;                   // 0..111
        const bool active = (nr < HID);
        const int n  = active ? nr : HID - 1;
        const int wq = n / 26, wi = n - wq * 26;

        half2_t Uc[4][13];
#pragma unroll
        for (int mm = 0; mm < 4; ++mm) {
            const half2_t* up = Ut4 + (size_t)((n * 4 + q) * 4 + mm) * 13;
#pragma unroll
            for (int r = 0; r < 13; ++r) Uc[mm][r] = up[r];
        }

        float c = 0.f;
        __syncthreads();                              // barrier #0

        const float scale = (q == 2) ? -LOG2E2 : -LOG2E;
        const float Aact  = (q == 2) ? 2.0f : 1.0f;
        const float Bact  = (q == 2) ? -1.0f : 0.0f;

        float hn_last = 0.f;

        auto step = [&](float zk, int cur) {
            const _Float16* hb = &h2[cur][q][0];
            f16x8   g0 = *(const f16x8*)(hb);
            f16x8   g1 = *(const f16x8*)(hb + 8);
            f16x8   g2 = *(const f16x8*)(hb + 16);
            half2_t g3 = *(const half2_t*)(hb + 24);
            half2_t hp[13];
            hp[0]  = __builtin_shufflevector(g0, g0, 0, 1);
            hp[1]  = __builtin_shufflevector(g0, g0, 2, 3);
            hp[2]  = __builtin_shufflevector(g0, g0, 4, 5);
            hp[3]  = __builtin_shufflevector(g0, g0, 6, 7);
            hp[4]  = __builtin_shufflevector(g1, g1, 0, 1);
            hp[5]  = __builtin_shufflevector(g1, g1, 2, 3);
            hp[6]  = __builtin_shufflevector(g1, g1, 4, 5);
            hp[7]  = __builtin_shufflevector(g1, g1, 6, 7);
            hp[8]  = __builtin_shufflevector(g2, g2, 0, 1);
            hp[9]  = __builtin_shufflevector(g2, g2, 2, 3);
            hp[10] = __builtin_shufflevector(g2, g2, 4, 5);
            hp[11] = __builtin_shufflevector(g2, g2, 6, 7);
            hp[12] = g3;

            float p0 = 0.f, p1 = 0.f, p2 = 0.f, p3 = 0.f;
#pragma unroll
            for (int r = 0; r < 13; ++r) {
                p0 = __builtin_amdgcn_fdot2(Uc[0][r], hp[r], p0, false);
                p1 = __builtin_amdgcn_fdot2(Uc[1][r], hp[r], p1, false);
                p2 = __builtin_amdgcn_fdot2(Uc[2][r], hp[r], p2, false);
                p3 = __builtin_amdgcn_fdot2(Uc[3][r], hp[r], p3, false);
            }
            float s0 = p0 + fdpp<DPP_X1>(p1);
            float s2 = p2 + fdpp<DPP_X1>(p3);
            float a  = s0 + fdpp<DPP_X2>(s2) + zk;

            float v = fmaf(Aact,
                           __builtin_amdgcn_rcpf(1.0f + __builtin_amdgcn_exp2f(scale * a)),
                           Bact);

            float bi = fdpp<DPP_B0>(v);
            float bf = fdpp<DPP_B1>(v);
            float bg = fdpp<DPP_B2>(v);
            float bo = fdpp<DPP_B3>(v);

            c = fmaf(bf, c, bi * bg);
            float tc = fmaf(2.0f,
                            __builtin_amdgcn_rcpf(1.0f + __builtin_amdgcn_exp2f(-LOG2E2 * c)),
                            -1.0f);
            float hn = bo * tc;
            if (q == 0 && active) h2[cur ^ 1][wq][wi] = (_Float16)hn;
            hn_last = hn;
            __syncthreads();
        };

        const int col = q * 112 + n;             // zbuf column (gate q, unit n)

        for (int j = 0; j < NWIN; ++j) {
            f16x8 zA = *(const f16x8*)&zbuf[j & 1][col * WSTEPS];
            f16x8 zB = *(const f16x8*)&zbuf[j & 1][col * WSTEPS + 8];
#pragma unroll
            for (int k = 0; k < 8; ++k) step((float)zA[k], k & 1);
#pragma unroll
            for (int k = 0; k < 8; ++k) step((float)zB[k], k & 1);
        }

        // ---- classifier tail ----
        if (q == 0 && active) hf32[n] = hn_last;
        __syncthreads();                              // tail barrier
        if (t < NCLS) {
            float acc2 = bd[t];
            const float4* h4 = (const float4*)hf32;
#pragma unroll 5
            for (int j4 = 0; j4 < 25; ++j4) {
                float4 hv = h4[j4];
                acc2 = fmaf(hv.x, Wd[(size_t)(4 * j4 + 0) * NCLS + t], acc2);
                acc2 = fmaf(hv.y, Wd[(size_t)(4 * j4 + 1) * NCLS + t], acc2);
                acc2 = fmaf(hv.z, Wd[(size_t)(4 * j4 + 2) * NCLS + t], acc2);
                acc2 = fmaf(hv.w, Wd[(size_t)(4 * j4 + 3) * NCLS + t], acc2);
            }
            out[(size_t)b * NCLS + t] = acc2;
        }
    }
}

// ---------------------------------------------------------------------------
extern "C" void kernel_launch(void* const* d_in, const int* in_sizes, int n_in,
                              void* d_out, int out_size, void* d_ws, size_t ws_size,
                              hipStream_t stream)
{
    const float* x    = (const float*)d_in[0];
    const float* W    = (const float*)d_in[1];
    const float* U    = (const float*)d_in[2];
    const float* bias = (const float*)d_in[3];
    const float* Wd   = (const float*)d_in[4];
    const float* bd   = (const float*)d_in[5];
    float* out = (float*)d_out;

    // ws (dwords): [Wf 43008][biasf 448][Ut4 20800]
    unsigned int* wsb = (unsigned int*)d_ws;
    unsigned short* Wf    = (unsigned short*)wsb;
    float*          biasf = (float*)(wsb + 43008);
    half2_t*        Ut4   = (half2_t*)(wsb + 43456);

    prep<<<419, 256, 0, stream>>>(W, U, bias, Wf, biasf, Ut4);
    scan_fused<<<BATCH, 576, 0, stream>>>(x, Wf, Ut4, biasf, Wd, bd, out);
}

// Round 12
// 307.426 us; speedup vs baseline: 1.1645x; 1.1606x over previous
//
#include <hip/hip_runtime.h>
#include <cstdint>
#include <cstddef>

#define S_LEN 384
#define BATCH 256
#define DIM   192     // HH*WW
#define HID   100
#define G4    400     // 4*HID
#define NCLS  250

#define WSTEPS 16     // z-tile window (MFMA M-dim = 16 timesteps)
#define NWIN   24     // 384 / 16
#define NTILES 28     // 448 cols (4 gates x 112) / 16
#define NKC    6      // 192 / 32 k-chunks

#define LOG2E  1.4426950408889634f
#define LOG2E2 2.8853900817779268f

typedef float    f32x4   __attribute__((ext_vector_type(4)));
typedef short    bf16x8  __attribute__((ext_vector_type(8)));
typedef _Float16 half2_t __attribute__((ext_vector_type(2)));
typedef _Float16 f16x4   __attribute__((ext_vector_type(4)));
typedef _Float16 f16x8   __attribute__((ext_vector_type(8)));

static __device__ __forceinline__ unsigned short f2bf(float f) {
    unsigned u = __float_as_uint(f);
    return (unsigned short)((u + 0x7FFFu + ((u >> 16) & 1u)) >> 16);   // RNE
}

// packed f32x2 -> bf16x2 (RNE), gfx950 has no builtin (learn_hip m240)
static __device__ __forceinline__ unsigned cvtpk(float a, float b) {
    unsigned r;
    asm("v_cvt_pk_bf16_f32 %0, %1, %2" : "=v"(r) : "v"(a), "v"(b));
    return r;
}

// DPP quad_perm cross-lane (VALU ~2cyc)
template<int CTRL>
static __device__ __forceinline__ float fdpp(float x) {
    return __int_as_float(
        __builtin_amdgcn_mov_dpp(__float_as_int(x), CTRL, 0xF, 0xF, true));
}
#define DPP_X1 0xB1   // quad_perm [1,0,3,2]  == xor 1
#define DPP_X2 0x4E   // quad_perm [2,3,0,1]  == xor 2
#define DPP_B0 0x00   // quad_perm [0,0,0,0]  broadcast lane0 of quad
#define DPP_B1 0x55   // quad_perm [1,1,1,1]
#define DPP_B2 0xAA   // quad_perm [2,2,2,2]
#define DPP_B3 0xFF   // quad_perm [3,3,3,3]

// ---------------------------------------------------------------------------
// Prep (verified): Wf — W as MFMA B-fragments (bf16):
//    Wf[((ct*6+kc)*64+lane)*8+e] = bf16(W[d][gate*100+unit]),
//    gate=ct/7, unit=(ct%7)*16+(lane&15) (0-pad unit>=100),
//    d = kc*32 + (lane>>4)*8 + e.
//  blocks [336,419): biasf[448] (tile-ordered bias, 0-padded) + Ut4
//    (verified U fragment layout for the scan).
// ---------------------------------------------------------------------------
__global__ void prep(const float* __restrict__ W, const float* __restrict__ U,
                     const float* __restrict__ bias,
                     unsigned short* __restrict__ Wf, float* __restrict__ biasf,
                     half2_t* __restrict__ Ut4)
{
    int bid = blockIdx.x;
    if (bid < 336) {
        int i = bid * 256 + threadIdx.x;          // 336*256 = 86016 exactly
        int e    = i & 7;
        int fi   = i >> 3;
        int lane = fi & 63;
        int ck   = fi >> 6;                       // (ct*6+kc) < 168
        int ct   = ck / 6, kc = ck - ct * 6;
        int m    = lane & 15, q = lane >> 4;
        int gate = ct / 7, jj = ct - gate * 7;
        int unit = jj * 16 + m;
        int d    = kc * 32 + q * 8 + e;           // < 192 always
        float v  = (unit < HID) ? W[(size_t)d * G4 + gate * HID + unit] : 0.0f;
        Wf[i] = f2bf(v);
    } else {
        int i = (bid - 336) * 256 + threadIdx.x;  // 448 + 20800 = 21248
        if (i < 448) {
            int ct = i >> 4, mm = i & 15;
            int gate = ct / 7, jj = ct - gate * 7;
            int unit = jj * 16 + mm;
            biasf[i] = (unit < HID) ? bias[gate * HID + unit] : 0.0f;
        } else {
            int i2 = i - 448;
            if (i2 >= 20800) return;
            int n    = i2 / 208;
            int rem  = i2 - n * 208;
            int q    = rem / 52;
            int rem2 = rem - q * 52;
            int mm   = rem2 / 13;
            int r    = rem2 - mm * 13;
            int col  = (q ^ mm) * HID + n;
            int j0   = 26 * q + 2 * r;
            half2_t v;
            v.x = (_Float16)(j0     < HID ? U[(size_t)j0       * G4 + col] : 0.0f);
            v.y = (_Float16)(j0 + 1 < HID ? U[(size_t)(j0 + 1) * G4 + col] : 0.0f);
            Ut4[i2] = v;
        }
    }
}

// ---------------------------------------------------------------------------
// Fused kernel (FINAL = verified round-7 best, 309us total):
//   Waves 0-6 (448 thr): the verified r1 scan core — z read from LDS zbuf
//     (16-step windows, double-buffered), one barrier per step.
//   Waves 7,8: producer waves, 14 tiles each per window, <=1 tile/slot.
//   Structural notes for future sessions:
//   - scan floor 176us = 384 x (~660cy lockstep VALU issue + ~450cy serial
//     recurrence chain: ds_read->fdot2 x13->exp2->rcp->DPP->fma->exp2->rcp
//     ->ds_write->barrier). Same-block waves cannot hide the chain.
//   - every fusion variant pays >=+400cy/step: the producer's load->MFMA
//     chain sits inside the same barrier interval. Source-level fixes
//     failed: RA demotes loop-invariant regs below need (r0-r4, fix only
//     via waves_per_eu(2,2) which 9 waves can't satisfy) and asm-pins
//     overflow the budget into scratch (r11: WRITE_SIZE 256KB->10.4MB).
//   - splitting back to gemm_pre + scan costs ~the same (317us, r8).
// ---------------------------------------------------------------------------
__global__ __launch_bounds__(576)
__attribute__((amdgpu_waves_per_eu(2)))
void scan_fused(const float* __restrict__ x, const unsigned short* __restrict__ Wf,
                const half2_t* __restrict__ Ut4, const float* __restrict__ biasf,
                const float* __restrict__ Wd, const float* __restrict__ bd,
                float* __restrict__ out)
{
    __shared__ __align__(16) _Float16 h2[2][4][40];
    __shared__ __align__(16) float hf32[HID];
    __shared__ __align__(16) _Float16 zbuf[2][448 * WSTEPS];   // 28.7 KB

    const int b    = blockIdx.x;
    const int t    = threadIdx.x;
    const int lane = t & 63;
    const int w    = t >> 6;

    if (t < 320) ((_Float16*)h2)[t] = (_Float16)0.f;   // zero both h bufs

    if (w >= 7) {
        // ===================== PRODUCER WAVES (2) =====================
        const int po = w - 7;            // 0: tiles [0,14), 1: tiles [14,28)
        const int pm = lane & 15;        // step row within window
        const int pq = lane >> 4;        // k-slice
        const float* __restrict__ xb = x + (size_t)b * S_LEN * DIM;
        float4 xv[NKC][2];               // next window's x rows
        bf16x8 Af[NKC];                  // current produce window's A frags

        auto loadx = [&](int s0) {
            int xr = s0 + pm;
#pragma unroll
            for (int kc = 0; kc < NKC; ++kc) {
                const float* p = xb + (size_t)xr * DIM + kc * 32 + pq * 8;
                xv[kc][0] = *(const float4*)p;
                xv[kc][1] = *(const float4*)(p + 4);
            }
        };
        auto cvt = [&]() {
#pragma unroll
            for (int kc = 0; kc < NKC; ++kc) {
                int4 ai;
                ai.x = (int)cvtpk(xv[kc][0].x, xv[kc][0].y);
                ai.y = (int)cvtpk(xv[kc][0].z, xv[kc][0].w);
                ai.z = (int)cvtpk(xv[kc][1].x, xv[kc][1].y);
                ai.w = (int)cvtpk(xv[kc][1].z, xv[kc][1].w);
                Af[kc] = *(bf16x8*)&ai;
            }
        };
        auto ptile = [&](int ct, int nb) {
            float bvv = biasf[ct * 16 + pm];          // L2-hot, hides in chain
            const unsigned short* bp = Wf + ((size_t)ct * (NKC * 64) + lane) * 8;
            f32x4 acc = {0.f, 0.f, 0.f, 0.f};
#pragma unroll
            for (int kc = 0; kc < NKC; ++kc) {
                bf16x8 Bf = *(const bf16x8*)(bp + (size_t)kc * 512);
                acc = __builtin_amdgcn_mfma_f32_16x16x32_bf16(Af[kc], Bf, acc, 0, 0, 0);
            }
            f16x4 zq;
            zq[0] = (_Float16)(acc[0] + bvv);
            zq[1] = (_Float16)(acc[1] + bvv);
            zq[2] = (_Float16)(acc[2] + bvv);
            zq[3] = (_Float16)(acc[3] + bvv);
            *(f16x4*)&zbuf[nb][(ct * 16 + pm) * WSTEPS + pq * 4] = zq;
        };

        // prologue: window 0 into zbuf[0]; prefetch x(window 1)
        loadx(0);
        cvt();
        for (int ct = po * 14; ct < po * 14 + 14; ++ct) ptile(ct, 0);
        loadx(WSTEPS);
        __syncthreads();                              // barrier #0

        for (int j = 0; j < NWIN; ++j) {
            const bool hasNext = (j < NWIN - 1);
            if (hasNext) cvt();                       // x(j+1) -> Af
            if (j < NWIN - 2) loadx((j + 2) * WSTEPS);
            const int nb = (j + 1) & 1;
#pragma unroll 1
            for (int k = 0; k < WSTEPS; ++k) {        // 16 slots == 16 barriers
                if (hasNext && k < 14) ptile(po * 14 + k, nb);
                __syncthreads();
            }
        }
        __syncthreads();                              // matches scan tail barrier
    } else {
        // ===================== SCAN WAVES (verified r1 core) =====================
        const int q  = t & 3;
        const int nr = t >> 2;                   // 0..111
        const bool active = (nr < HID);
        const int n  = active ? nr : HID - 1;
        const int wq = n / 26, wi = n - wq * 26;

        half2_t Uc[4][13];
#pragma unroll
        for (int mm = 0; mm < 4; ++mm) {
            const half2_t* up = Ut4 + (size_t)((n * 4 + q) * 4 + mm) * 13;
#pragma unroll
            for (int r = 0; r < 13; ++r) Uc[mm][r] = up[r];
        }

        float c = 0.f;
        __syncthreads();                              // barrier #0

        const float scale = (q == 2) ? -LOG2E2 : -LOG2E;
        const float Aact  = (q == 2) ? 2.0f : 1.0f;
        const float Bact  = (q == 2) ? -1.0f : 0.0f;

        float hn_last = 0.f;

        auto step = [&](float zk, int cur) {
            const _Float16* hb = &h2[cur][q][0];
            f16x8   g0 = *(const f16x8*)(hb);
            f16x8   g1 = *(const f16x8*)(hb + 8);
            f16x8   g2 = *(const f16x8*)(hb + 16);
            half2_t g3 = *(const half2_t*)(hb + 24);
            half2_t hp[13];
            hp[0]  = __builtin_shufflevector(g0, g0, 0, 1);
            hp[1]  = __builtin_shufflevector(g0, g0, 2, 3);
            hp[2]  = __builtin_shufflevector(g0, g0, 4, 5);
            hp[3]  = __builtin_shufflevector(g0, g0, 6, 7);
            hp[4]  = __builtin_shufflevector(g1, g1, 0, 1);
            hp[5]  = __builtin_shufflevector(g1, g1, 2, 3);
            hp[6]  = __builtin_shufflevector(g1, g1, 4, 5);
            hp[7]  = __builtin_shufflevector(g1, g1, 6, 7);
            hp[8]  = __builtin_shufflevector(g2, g2, 0, 1);
            hp[9]  = __builtin_shufflevector(g2, g2, 2, 3);
            hp[10] = __builtin_shufflevector(g2, g2, 4, 5);
            hp[11] = __builtin_shufflevector(g2, g2, 6, 7);
            hp[12] = g3;

            float p0 = 0.f, p1 = 0.f, p2 = 0.f, p3 = 0.f;
#pragma unroll
            for (int r = 0; r < 13; ++r) {
                p0 = __builtin_amdgcn_fdot2(Uc[0][r], hp[r], p0, false);
                p1 = __builtin_amdgcn_fdot2(Uc[1][r], hp[r], p1, false);
                p2 = __builtin_amdgcn_fdot2(Uc[2][r], hp[r], p2, false);
                p3 = __builtin_amdgcn_fdot2(Uc[3][r], hp[r], p3, false);
            }
            float s0 = p0 + fdpp<DPP_X1>(p1);
            float s2 = p2 + fdpp<DPP_X1>(p3);
            float a  = s0 + fdpp<DPP_X2>(s2) + zk;

            float v = fmaf(Aact,
                           __builtin_amdgcn_rcpf(1.0f + __builtin_amdgcn_exp2f(scale * a)),
                           Bact);

            float bi = fdpp<DPP_B0>(v);
            float bf = fdpp<DPP_B1>(v);
            float bg = fdpp<DPP_B2>(v);
            float bo = fdpp<DPP_B3>(v);

            c = fmaf(bf, c, bi * bg);
            float tc = fmaf(2.0f,
                            __builtin_amdgcn_rcpf(1.0f + __builtin_amdgcn_exp2f(-LOG2E2 * c)),
                            -1.0f);
            float hn = bo * tc;
            if (q == 0 && active) h2[cur ^ 1][wq][wi] = (_Float16)hn;
            hn_last = hn;
            __syncthreads();
        };

        const int col = q * 112 + n;             // zbuf column (gate q, unit n)

        for (int j = 0; j < NWIN; ++j) {
            f16x8 zA = *(const f16x8*)&zbuf[j & 1][col * WSTEPS];
            f16x8 zB = *(const f16x8*)&zbuf[j & 1][col * WSTEPS + 8];
#pragma unroll
            for (int k = 0; k < 8; ++k) step((float)zA[k], k & 1);
#pragma unroll
            for (int k = 0; k < 8; ++k) step((float)zB[k], k & 1);
        }

        // ---- classifier tail ----
        if (q == 0 && active) hf32[n] = hn_last;
        __syncthreads();                              // tail barrier
        if (t < NCLS) {
            float acc2 = bd[t];
            const float4* h4 = (const float4*)hf32;
#pragma unroll 5
            for (int j4 = 0; j4 < 25; ++j4) {
                float4 hv = h4[j4];
                acc2 = fmaf(hv.x, Wd[(size_t)(4 * j4 + 0) * NCLS + t], acc2);
                acc2 = fmaf(hv.y, Wd[(size_t)(4 * j4 + 1) * NCLS + t], acc2);
                acc2 = fmaf(hv.z, Wd[(size_t)(4 * j4 + 2) * NCLS + t], acc2);
                acc2 = fmaf(hv.w, Wd[(size_t)(4 * j4 + 3) * NCLS + t], acc2);
            }
            out[(size_t)b * NCLS + t] = acc2;
        }
    }
}

// ---------------------------------------------------------------------------
extern "C" void kernel_launch(void* const* d_in, const int* in_sizes, int n_in,
                              void* d_out, int out_size, void* d_ws, size_t ws_size,
                              hipStream_t stream)
{
    const float* x    = (const float*)d_in[0];
    const float* W    = (const float*)d_in[1];
    const float* U    = (const float*)d_in[2];
    const float* bias = (const float*)d_in[3];
    const float* Wd   = (const float*)d_in[4];
    const float* bd   = (const float*)d_in[5];
    float* out = (float*)d_out;

    // ws (dwords): [Wf 43008][biasf 448][Ut4 20800]
    unsigned int* wsb = (unsigned int*)d_ws;
    unsigned short* Wf    = (unsigned short*)wsb;
    float*          biasf = (float*)(wsb + 43008);
    half2_t*        Ut4   = (half2_t*)(wsb + 43456);

    prep<<<419, 256, 0, stream>>>(W, U, bias, Wf, biasf, Ut4);
    scan_fused<<<BATCH, 576, 0, stream>>>(x, Wf, Ut4, biasf, Wd, bd, out);
}